// Round 3
// baseline (652.044 us; speedup 1.0000x reference)
//
#include <hip/hip_runtime.h>

// CategoryRouter: per-token routed 2-layer MLP head + softmax.
// B=4,S=1024 (T=4096 tokens), D=768, F=3072, V=2048, R=8.
// Round 3: BM 128->64. Round-2 counters showed GEMM latency-bound
// (Occupancy 13%, MfmaUtil 14%, HBM 22%) with only ~2.3 blocks/CU;
// BM=64 doubles grid to ~4.5 blocks/CU (m102 shape-curve regime).

typedef __attribute__((ext_vector_type(8))) short    s16x8;
typedef __attribute__((ext_vector_type(4))) float    f32x4;

#define T_TOK 4096
#define D_    768
#define F_    3072
#define V_    2048
#define R_    8
#define BM    64
#define BN    128
#define BK    64
#define MAXTILES 72      // 4096/64 + 8
#define PADROWS  4608    // 4096 + 8*63 rounded to 64

// ---- workspace layout (bytes) ----
#define OFF_COUNTS  ((size_t)0)     // 8 int
#define OFF_CURS    ((size_t)64)    // 8 int
#define OFF_PADOFF  ((size_t)128)   // 9 int
#define OFF_NT      ((size_t)192)   // 1 int
#define OFF_TROUTE  ((size_t)256)   // MAXTILES int
#define OFF_TROW    ((size_t)1024)  // MAXTILES int
#define OFF_TOK     ((size_t)4096)                                  // PADROWS int
#define OFF_XG      ((size_t)32768)                                 // PADROWS*D bf16
#define OFF_H       (OFF_XG  + (size_t)PADROWS*D_*2)                // PADROWS*F bf16
#define OFF_W1T     (OFF_H   + (size_t)PADROWS*F_*2)                // R*F*D bf16 ([R][F][D])
#define OFF_W2T     (OFF_W1T + (size_t)R_*F_*D_*2)                  // R*V*F bf16 ([R][V][F])

static __device__ __forceinline__ unsigned short f2bf(float f) {
  union { float f; unsigned int u; } x; x.f = f;
  unsigned int r = x.u + 0x7FFFu + ((x.u >> 16) & 1u);   // RNE
  return (unsigned short)(r >> 16);
}

// global -> LDS direct copy, 16B per lane. LDS dest must be wave-uniform
// base; HW writes base + lane*16 (m104/m108). Global src is per-lane.
static __device__ __forceinline__ void gload_lds16(const unsigned short* g,
                                                   unsigned short* l) {
  __builtin_amdgcn_global_load_lds(
      (const __attribute__((address_space(1))) unsigned int*)(const void*)g,
      (__attribute__((address_space(3))) unsigned int*)(void*)l, 16, 0, 0);
}

// ---------------- routing ----------------
__global__ void cr_count(const int* __restrict__ route, int* __restrict__ counts) {
  int t = blockIdx.x * blockDim.x + threadIdx.x;
  if (t < T_TOK) atomicAdd(&counts[route[t]], 1);
}

__global__ void cr_plan(const int* __restrict__ counts, int* __restrict__ padOff,
                        int* __restrict__ nTiles, int* __restrict__ tRoute,
                        int* __restrict__ tRow) {
  if (threadIdx.x != 0 || blockIdx.x != 0) return;
  int off = 0, tiles = 0;
  for (int r = 0; r < R_; ++r) {
    padOff[r] = off;
    int nt = (counts[r] + BM - 1) / BM;
    for (int i = 0; i < nt; ++i) { tRoute[tiles] = r; tRow[tiles] = off + i * BM; ++tiles; }
    off += nt * BM;
  }
  padOff[R_] = off;
  *nTiles = tiles;
}

// one block (192 thr) per token: claim slot, gather+convert its x row to bf16
__global__ void cr_scatter(const float* __restrict__ X, const int* __restrict__ route,
                           const int* __restrict__ padOff, int* __restrict__ curs,
                           int* __restrict__ tok, unsigned short* __restrict__ Xg) {
  __shared__ int spos;
  int t = blockIdx.x;
  if (threadIdx.x == 0) {
    int r = route[t];
    int p = padOff[r] + atomicAdd(&curs[r], 1);
    tok[p] = t;
    spos = p;
  }
  __syncthreads();
  int pos = spos;
  float4 v = reinterpret_cast<const float4*>(X + (size_t)t * D_)[threadIdx.x];
  ushort4 o;
  o.x = f2bf(v.x); o.y = f2bf(v.y); o.z = f2bf(v.z); o.w = f2bf(v.w);
  *reinterpret_cast<ushort4*>(Xg + (size_t)pos * D_ + threadIdx.x * 4) = o;
}

// ---------------- weight transpose + fp32->bf16 ----------------
// in: W [R][K][N] fp32 ; out: Wt [R][N][K] bf16   (64x64 tiles, 256 thr)
template <int K, int N>
__global__ void cr_transpose(const float* __restrict__ W, unsigned short* __restrict__ Wt) {
  __shared__ float tile[64][65];
  int r = blockIdx.z;
  const float* Wr = W + (size_t)r * K * N;
  unsigned short* Wtr = Wt + (size_t)r * N * K;
  int k0 = blockIdx.x * 64, n0 = blockIdx.y * 64;
  int t = threadIdx.x;
  int cb = (t & 15) * 4, rb = t >> 4;
#pragma unroll
  for (int i = 0; i < 4; ++i) {
    int k = rb + i * 16;
    float4 v = *reinterpret_cast<const float4*>(Wr + (size_t)(k0 + k) * N + n0 + cb);
    tile[k][cb] = v.x; tile[k][cb + 1] = v.y; tile[k][cb + 2] = v.z; tile[k][cb + 3] = v.w;
  }
  __syncthreads();
  int n = t >> 2, kc = (t & 3) * 16;
  alignas(16) unsigned short o[16];
#pragma unroll
  for (int j = 0; j < 16; ++j) o[j] = f2bf(tile[kc + j][n]);
  unsigned short* dst = Wtr + (size_t)(n0 + n) * K + k0 + kc;
  *reinterpret_cast<s16x8*>(dst)     = *reinterpret_cast<const s16x8*>(&o[0]);
  *reinterpret_cast<s16x8*>(dst + 8) = *reinterpret_cast<const s16x8*>(&o[8]);
}

// ---------------- grouped GEMM ----------------
// A [PADROWS][K] bf16 row-major; Wt [R][N][K] bf16 (K-contiguous per output col).
// MODE 0: H = relu(A@W + b)  (bf16, contiguous padded rows)
// MODE 1: out[tok[row]] = A@W + b  (fp32 scatter)
// Tile 64x128, BK=64; 4 waves, each owns 64 rows x 32 cols (acc[4][2]).
template <int K, int N, int MODE>
__global__ __launch_bounds__(256) void cr_gemm(
    const unsigned short* __restrict__ A, const unsigned short* __restrict__ Wt,
    const float* __restrict__ bias, const int* __restrict__ nTiles,
    const int* __restrict__ tRoute, const int* __restrict__ tRow,
    const int* __restrict__ tok, unsigned short* __restrict__ Hout,
    float* __restrict__ Fout) {
  int mt = blockIdx.x;
  if (mt >= *nTiles) return;
  int route = tRoute[mt], row0 = tRow[mt];
  int col0 = blockIdx.y * BN;
  const unsigned short* Ag = A + (size_t)row0 * K;
  const unsigned short* Bg = Wt + ((size_t)route * N + col0) * K;

  __shared__ __align__(16) unsigned short As[BM * BK];  // [row][k]  8 KB
  __shared__ __align__(16) unsigned short Bs[BN * BK];  // [col][k] 16 KB

  int tid = threadIdx.x, lane = tid & 63, w = tid >> 6;
  int srow = lane >> 3;          // row within 8-row chunk (staging)
  int scol = (lane & 7) * 8;     // k element within BK (staging)
  int frow = lane & 15;          // fragment row/col
  int fk   = (lane >> 4) * 8;    // fragment k base

  f32x4 acc[4][2] = {};

  for (int kt = 0; kt < K; kt += BK) {
    // 24 chunks of 8 rows x 64 k (1 KB each): 0..7 -> As, 8..23 -> Bs.
    // chunk = j*4+w is wave-uniform; lane LDS offset = 16*lane bytes.
#pragma unroll
    for (int j = 0; j < 6; ++j) {
      int chunk = j * 4 + w;
      if (chunk < 8) {
        int rrow = chunk * 8 + srow;
        gload_lds16(Ag + (size_t)rrow * K + kt + scol, As + chunk * 512);
      } else {
        int bcol = (chunk - 8) * 8 + srow;
        gload_lds16(Bg + (size_t)bcol * K + kt + scol, Bs + (chunk - 8) * 512);
      }
    }
    __syncthreads();
#pragma unroll
    for (int kk = 0; kk < 2; ++kk) {
      s16x8 a[4], b[2];
#pragma unroll
      for (int mi = 0; mi < 4; ++mi)
        a[mi] = *reinterpret_cast<const s16x8*>(&As[(mi * 16 + frow) * BK + kk * 32 + fk]);
#pragma unroll
      for (int ni = 0; ni < 2; ++ni)
        b[ni] = *reinterpret_cast<const s16x8*>(&Bs[(w * 32 + ni * 16 + frow) * BK + kk * 32 + fk]);
#pragma unroll
      for (int mi = 0; mi < 4; ++mi)
#pragma unroll
        for (int ni = 0; ni < 2; ++ni)
          acc[mi][ni] = __builtin_amdgcn_mfma_f32_16x16x32_bf16(a[mi], b[ni], acc[mi][ni], 0, 0, 0);
    }
    __syncthreads();
  }

  // epilogue: C/D layout col=lane&15, row=(lane>>4)*4+j  (m89/m91-verified)
  int crow = (lane >> 4) * 4;
  int ccol = lane & 15;
#pragma unroll
  for (int mi = 0; mi < 4; ++mi) {
#pragma unroll
    for (int ni = 0; ni < 2; ++ni) {
      int gcol = col0 + w * 32 + ni * 16 + ccol;
      float bv = bias[(size_t)route * N + gcol];
#pragma unroll
      for (int j = 0; j < 4; ++j) {
        int prow = row0 + mi * 16 + crow + j;
        float v = acc[mi][ni][j] + bv;
        if (MODE == 0) {
          v = fmaxf(v, 0.f);
          Hout[(size_t)prow * N + gcol] = f2bf(v);
        } else {
          int tk = tok[prow];
          if (tk >= 0) Fout[(size_t)tk * N + gcol] = v;
        }
      }
    }
  }
}

// ---------------- softmax (in place over V=2048, one block per token) ----------
__global__ void cr_softmax(float* __restrict__ out) {
  int row = blockIdx.x;
  float* p = out + (size_t)row * V_;
  int t = threadIdx.x;
  float4 v0 = reinterpret_cast<float4*>(p)[t];
  float4 v1 = reinterpret_cast<float4*>(p)[t + 256];
  float m = fmaxf(fmaxf(fmaxf(v0.x, v0.y), fmaxf(v0.z, v0.w)),
                  fmaxf(fmaxf(v1.x, v1.y), fmaxf(v1.z, v1.w)));
#pragma unroll
  for (int o = 32; o; o >>= 1) m = fmaxf(m, __shfl_xor(m, o));
  __shared__ float sm[4], ss[4];
  int w = t >> 6;
  if ((t & 63) == 0) sm[w] = m;
  __syncthreads();
  m = fmaxf(fmaxf(sm[0], sm[1]), fmaxf(sm[2], sm[3]));
  v0.x = expf(v0.x - m); v0.y = expf(v0.y - m); v0.z = expf(v0.z - m); v0.w = expf(v0.w - m);
  v1.x = expf(v1.x - m); v1.y = expf(v1.y - m); v1.z = expf(v1.z - m); v1.w = expf(v1.w - m);
  float s = v0.x + v0.y + v0.z + v0.w + v1.x + v1.y + v1.z + v1.w;
#pragma unroll
  for (int o = 32; o; o >>= 1) s += __shfl_xor(s, o);
  if ((t & 63) == 0) ss[w] = s;
  __syncthreads();
  s = ss[0] + ss[1] + ss[2] + ss[3];
  float inv = 1.f / s;
  v0.x *= inv; v0.y *= inv; v0.z *= inv; v0.w *= inv;
  v1.x *= inv; v1.y *= inv; v1.z *= inv; v1.w *= inv;
  reinterpret_cast<float4*>(p)[t] = v0;
  reinterpret_cast<float4*>(p)[t + 256] = v1;
}

extern "C" void kernel_launch(void* const* d_in, const int* in_sizes, int n_in,
                              void* d_out, int out_size, void* d_ws, size_t ws_size,
                              hipStream_t stream) {
  const float* X      = (const float*)d_in[0];
  const int*   route  = (const int*)d_in[1];
  const float* W1     = (const float*)d_in[2];
  const float* b1     = (const float*)d_in[3];
  const float* W2     = (const float*)d_in[4];
  const float* b2     = (const float*)d_in[5];
  float*       out    = (float*)d_out;
  char*        ws     = (char*)d_ws;

  int* counts = (int*)(ws + OFF_COUNTS);
  int* curs   = (int*)(ws + OFF_CURS);
  int* padOff = (int*)(ws + OFF_PADOFF);
  int* nT     = (int*)(ws + OFF_NT);
  int* tRoute = (int*)(ws + OFF_TROUTE);
  int* tRow   = (int*)(ws + OFF_TROW);
  int* tok    = (int*)(ws + OFF_TOK);
  unsigned short* Xg  = (unsigned short*)(ws + OFF_XG);
  unsigned short* H   = (unsigned short*)(ws + OFF_H);
  unsigned short* W1T = (unsigned short*)(ws + OFF_W1T);
  unsigned short* W2T = (unsigned short*)(ws + OFF_W2T);

  hipMemsetAsync(ws, 0, 4096, stream);                              // counters/meta
  hipMemsetAsync(ws + OFF_TOK, 0xFF, (size_t)PADROWS * 4, stream);  // tok = -1
  hipMemsetAsync(ws + OFF_XG, 0, (size_t)PADROWS * D_ * 2, stream); // zero padding rows

  cr_count<<<T_TOK / 256, 256, 0, stream>>>(route, counts);
  cr_plan<<<1, 64, 0, stream>>>(counts, padOff, nT, tRoute, tRow);
  cr_scatter<<<T_TOK, 192, 0, stream>>>(X, route, padOff, curs, tok, Xg);

  cr_transpose<D_, F_><<<dim3(D_ / 64, F_ / 64, R_), 256, 0, stream>>>(W1, W1T);
  cr_transpose<F_, V_><<<dim3(F_ / 64, V_ / 64, R_), 256, 0, stream>>>(W2, W2T);

  cr_gemm<D_, F_, 0><<<dim3(MAXTILES, F_ / BN), 256, 0, stream>>>(
      Xg, W1T, b1, nT, tRoute, tRow, tok, H, nullptr);
  cr_gemm<F_, V_, 1><<<dim3(MAXTILES, V_ / BN), 256, 0, stream>>>(
      H, W2T, b2, nT, tRoute, tRow, tok, nullptr, out);

  cr_softmax<<<T_TOK, 256, 0, stream>>>(out);
}

// Round 5
// 646.403 us; speedup vs baseline: 1.0087x; 1.0087x over previous
//
#include <hip/hip_runtime.h>

// CategoryRouter: per-token routed 2-layer MLP head + softmax.
// B=4,S=1024 (T=4096 tokens), D=768, F=3072, V=2048, R=8.
// Round 4/5: (1) XCD-ownership block mapping — each XCD owns a fixed 9-tile
// M-subset (A-slice 3.4MB fits its 4MiB L2; round-3 FETCH showed A re-read
// 16x from HBM). (2) 2-phase double-buffered prefetch (T3-minimum):
// STAGE(next) before compute(cur), one barrier per K-step.

typedef __attribute__((ext_vector_type(8))) short    s16x8;
typedef __attribute__((ext_vector_type(4))) float    f32x4;

#define T_TOK 4096
#define D_    768
#define F_    3072
#define V_    2048
#define R_    8
#define BM    64
#define BN    128
#define BK    64
#define MAXTILES 72      // 4096/64 + 8  (multiple of 8)
#define NMTX     9       // MAXTILES / 8 tiles owned per XCD
#define PADROWS  4608    // 4096 + 8*63 rounded to 64

// ---- workspace layout (bytes) ----
#define OFF_COUNTS  ((size_t)0)     // 8 int
#define OFF_CURS    ((size_t)64)    // 8 int
#define OFF_PADOFF  ((size_t)128)   // 9 int
#define OFF_NT      ((size_t)192)   // 1 int
#define OFF_TROUTE  ((size_t)256)   // MAXTILES int
#define OFF_TROW    ((size_t)1024)  // MAXTILES int
#define OFF_TOK     ((size_t)4096)                                  // PADROWS int
#define OFF_XG      ((size_t)32768)                                 // PADROWS*D bf16
#define OFF_H       (OFF_XG  + (size_t)PADROWS*D_*2)                // PADROWS*F bf16
#define OFF_W1T     (OFF_H   + (size_t)PADROWS*F_*2)                // R*F*D bf16 ([R][F][D])
#define OFF_W2T     (OFF_W1T + (size_t)R_*F_*D_*2)                  // R*V*F bf16 ([R][V][K])

static __device__ __forceinline__ unsigned short f2bf(float f) {
  union { float f; unsigned int u; } x; x.f = f;
  unsigned int r = x.u + 0x7FFFu + ((x.u >> 16) & 1u);   // RNE
  return (unsigned short)(r >> 16);
}

// global -> LDS direct copy, 16B per lane. LDS dest must be wave-uniform
// base; HW writes base + lane*16 (m104/m108). Global src is per-lane.
static __device__ __forceinline__ void gload_lds16(const unsigned short* g,
                                                   unsigned short* l) {
  __builtin_amdgcn_global_load_lds(
      (const __attribute__((address_space(1))) unsigned int*)(const void*)g,
      (__attribute__((address_space(3))) unsigned int*)(void*)l, 16, 0, 0);
}

// ---------------- routing ----------------
__global__ void cr_count(const int* __restrict__ route, int* __restrict__ counts) {
  int t = blockIdx.x * blockDim.x + threadIdx.x;
  if (t < T_TOK) atomicAdd(&counts[route[t]], 1);
}

__global__ void cr_plan(const int* __restrict__ counts, int* __restrict__ padOff,
                        int* __restrict__ nTiles, int* __restrict__ tRoute,
                        int* __restrict__ tRow) {
  if (threadIdx.x != 0 || blockIdx.x != 0) return;
  int off = 0, tiles = 0;
  for (int r = 0; r < R_; ++r) {
    padOff[r] = off;
    int nt = (counts[r] + BM - 1) / BM;
    for (int i = 0; i < nt; ++i) { tRoute[tiles] = r; tRow[tiles] = off + i * BM; ++tiles; }
    off += nt * BM;
  }
  padOff[R_] = off;
  *nTiles = tiles;
}

// one block (192 thr) per token: claim slot, gather+convert its x row to bf16
__global__ void cr_scatter(const float* __restrict__ X, const int* __restrict__ route,
                           const int* __restrict__ padOff, int* __restrict__ curs,
                           int* __restrict__ tok, unsigned short* __restrict__ Xg) {
  __shared__ int spos;
  int t = blockIdx.x;
  if (threadIdx.x == 0) {
    int r = route[t];
    int p = padOff[r] + atomicAdd(&curs[r], 1);
    tok[p] = t;
    spos = p;
  }
  __syncthreads();
  int pos = spos;
  float4 v = reinterpret_cast<const float4*>(X + (size_t)t * D_)[threadIdx.x];
  ushort4 o;
  o.x = f2bf(v.x); o.y = f2bf(v.y); o.z = f2bf(v.z); o.w = f2bf(v.w);
  *reinterpret_cast<ushort4*>(Xg + (size_t)pos * D_ + threadIdx.x * 4) = o;
}

// ---------------- weight transpose + fp32->bf16 ----------------
// in: W [R][K][N] fp32 ; out: Wt [R][N][K] bf16   (64x64 tiles, 256 thr)
template <int K, int N>
__global__ void cr_transpose(const float* __restrict__ W, unsigned short* __restrict__ Wt) {
  __shared__ float tile[64][65];
  int r = blockIdx.z;
  const float* Wr = W + (size_t)r * K * N;
  unsigned short* Wtr = Wt + (size_t)r * N * K;
  int k0 = blockIdx.x * 64, n0 = blockIdx.y * 64;
  int t = threadIdx.x;
  int cb = (t & 15) * 4, rb = t >> 4;
#pragma unroll
  for (int i = 0; i < 4; ++i) {
    int k = rb + i * 16;
    float4 v = *reinterpret_cast<const float4*>(Wr + (size_t)(k0 + k) * N + n0 + cb);
    tile[k][cb] = v.x; tile[k][cb + 1] = v.y; tile[k][cb + 2] = v.z; tile[k][cb + 3] = v.w;
  }
  __syncthreads();
  int n = t >> 2, kc = (t & 3) * 16;
  alignas(16) unsigned short o[16];
#pragma unroll
  for (int j = 0; j < 16; ++j) o[j] = f2bf(tile[kc + j][n]);
  unsigned short* dst = Wtr + (size_t)(n0 + n) * K + k0 + kc;
  *reinterpret_cast<s16x8*>(dst)     = *reinterpret_cast<const s16x8*>(&o[0]);
  *reinterpret_cast<s16x8*>(dst + 8) = *reinterpret_cast<const s16x8*>(&o[8]);
}

// ---------------- grouped GEMM ----------------
// A [PADROWS][K] bf16 row-major; Wt [R][N][K] bf16 (K-contiguous per col).
// MODE 0: H = relu(A@W + b)  (bf16). MODE 1: out[tok[row]] = A@W + b (fp32).
// Tile 64x128, BK=64, 4 waves (each 64 rows x 32 cols, acc[4][2]).
// 1-D grid MAXTILES*(N/BN); XCD bid&7 owns mt strided subset; dbuf prefetch.
template <int K, int N, int MODE>
__global__ __launch_bounds__(256) void cr_gemm(
    const unsigned short* __restrict__ A, const unsigned short* __restrict__ Wt,
    const float* __restrict__ bias, const int* __restrict__ nTiles,
    const int* __restrict__ tRoute, const int* __restrict__ tRow,
    const int* __restrict__ tok, unsigned short* __restrict__ Hout,
    float* __restrict__ Fout) {
  // XCD-ownership decode: blocks with bid%8==x land on XCD x (round-robin
  // dispatch); give that XCD a fixed M-tile subset and sweep y within it.
  int bid = blockIdx.x;
  int xcd = bid & 7;
  int widx = bid >> 3;           // 0 .. NMTX*(N/BN)-1
  int mtl = widx % NMTX;
  int y   = widx / NMTX;
  int mt  = mtl * 8 + xcd;       // strided: empty tail tiles spread evenly
  if (mt >= *nTiles) return;
  int route = tRoute[mt], row0 = tRow[mt];
  int col0 = y * BN;
  const unsigned short* Ag = A + (size_t)row0 * K;
  const unsigned short* Bg = Wt + ((size_t)route * N + col0) * K;

  __shared__ __align__(16) unsigned short As[2][BM * BK];  // [row][k]  2x8 KB
  __shared__ __align__(16) unsigned short Bs[2][BN * BK];  // [col][k]  2x16 KB

  int tid = threadIdx.x, lane = tid & 63, w = tid >> 6;
  int srow = lane >> 3;          // row within 8-row chunk (staging)
  int scol = (lane & 7) * 8;     // k element within BK (staging)
  int frow = lane & 15;          // fragment row/col
  int fk   = (lane >> 4) * 8;    // fragment k base

  f32x4 acc[4][2] = {};

  // 24 chunks of 8 rows x 64 k (1 KB each): 0..7 -> As, 8..23 -> Bs.
  // chunk = j*4+w is wave-uniform; lane LDS offset = 16*lane bytes.
  auto stage = [&](int buf, int kt) {
#pragma unroll
    for (int j = 0; j < 6; ++j) {
      int chunk = j * 4 + w;
      if (chunk < 8) {
        gload_lds16(Ag + (size_t)(chunk * 8 + srow) * K + kt + scol,
                    &As[buf][chunk * 512]);
      } else {
        gload_lds16(Bg + (size_t)((chunk - 8) * 8 + srow) * K + kt + scol,
                    &Bs[buf][(chunk - 8) * 512]);
      }
    }
  };
  auto compute = [&](int buf) {
#pragma unroll
    for (int kk = 0; kk < 2; ++kk) {
      s16x8 a[4], b[2];
#pragma unroll
      for (int mi = 0; mi < 4; ++mi)
        a[mi] = *reinterpret_cast<const s16x8*>(
            &As[buf][(mi * 16 + frow) * BK + kk * 32 + fk]);
#pragma unroll
      for (int ni = 0; ni < 2; ++ni)
        b[ni] = *reinterpret_cast<const s16x8*>(
            &Bs[buf][(w * 32 + ni * 16 + frow) * BK + kk * 32 + fk]);
#pragma unroll
      for (int mi = 0; mi < 4; ++mi)
#pragma unroll
        for (int ni = 0; ni < 2; ++ni)
          acc[mi][ni] = __builtin_amdgcn_mfma_f32_16x16x32_bf16(
              a[mi], b[ni], acc[mi][ni], 0, 0, 0);
    }
  };

  // 2-phase pipeline: stage(next) issued BEFORE compute(cur); the single
  // __syncthreads per K-step drains vmcnt (next tile ready) and fences the
  // LDS reads of cur before it is overwritten next iteration.
  stage(0, 0);
  __syncthreads();
  int cur = 0;
  for (int kt = BK; kt < K; kt += BK) {
    stage(cur ^ 1, kt);
    compute(cur);
    __syncthreads();
    cur ^= 1;
  }
  compute(cur);

  // epilogue: C/D layout col=lane&15, row=(lane>>4)*4+j  (m89/m91-verified)
  int crow = (lane >> 4) * 4;
  int ccol = lane & 15;
#pragma unroll
  for (int mi = 0; mi < 4; ++mi) {
#pragma unroll
    for (int ni = 0; ni < 2; ++ni) {
      int gcol = col0 + w * 32 + ni * 16 + ccol;
      float bv = bias[(size_t)route * N + gcol];
#pragma unroll
      for (int j = 0; j < 4; ++j) {
        int prow = row0 + mi * 16 + crow + j;
        float v = acc[mi][ni][j] + bv;
        if (MODE == 0) {
          v = fmaxf(v, 0.f);
          Hout[(size_t)prow * N + gcol] = f2bf(v);
        } else {
          int tk = tok[prow];
          if (tk >= 0) Fout[(size_t)tk * N + gcol] = v;
        }
      }
    }
  }
}

// ---------------- softmax (in place over V=2048, one block per token) ----------
__global__ void cr_softmax(float* __restrict__ out) {
  int row = blockIdx.x;
  float* p = out + (size_t)row * V_;
  int t = threadIdx.x;
  float4 v0 = reinterpret_cast<float4*>(p)[t];
  float4 v1 = reinterpret_cast<float4*>(p)[t + 256];
  float m = fmaxf(fmaxf(fmaxf(v0.x, v0.y), fmaxf(v0.z, v0.w)),
                  fmaxf(fmaxf(v1.x, v1.y), fmaxf(v1.z, v1.w)));
#pragma unroll
  for (int o = 32; o; o >>= 1) m = fmaxf(m, __shfl_xor(m, o));
  __shared__ float sm[4], ss[4];
  int w = t >> 6;
  if ((t & 63) == 0) sm[w] = m;
  __syncthreads();
  m = fmaxf(fmaxf(sm[0], sm[1]), fmaxf(sm[2], sm[3]));
  v0.x = expf(v0.x - m); v0.y = expf(v0.y - m); v0.z = expf(v0.z - m); v0.w = expf(v0.w - m);
  v1.x = expf(v1.x - m); v1.y = expf(v1.y - m); v1.z = expf(v1.z - m); v1.w = expf(v1.w - m);
  float s = v0.x + v0.y + v0.z + v0.w + v1.x + v1.y + v1.z + v1.w;
#pragma unroll
  for (int o = 32; o; o >>= 1) s += __shfl_xor(s, o);
  if ((t & 63) == 0) ss[w] = s;
  __syncthreads();
  s = ss[0] + ss[1] + ss[2] + ss[3];
  float inv = 1.f / s;
  v0.x *= inv; v0.y *= inv; v0.z *= inv; v0.w *= inv;
  v1.x *= inv; v1.y *= inv; v1.z *= inv; v1.w *= inv;
  reinterpret_cast<float4*>(p)[t] = v0;
  reinterpret_cast<float4*>(p)[t + 256] = v1;
}

extern "C" void kernel_launch(void* const* d_in, const int* in_sizes, int n_in,
                              void* d_out, int out_size, void* d_ws, size_t ws_size,
                              hipStream_t stream) {
  const float* X      = (const float*)d_in[0];
  const int*   route  = (const int*)d_in[1];
  const float* W1     = (const float*)d_in[2];
  const float* b1     = (const float*)d_in[3];
  const float* W2     = (const float*)d_in[4];
  const float* b2     = (const float*)d_in[5];
  float*       out    = (float*)d_out;
  char*        ws     = (char*)d_ws;

  int* counts = (int*)(ws + OFF_COUNTS);
  int* curs   = (int*)(ws + OFF_CURS);
  int* padOff = (int*)(ws + OFF_PADOFF);
  int* nT     = (int*)(ws + OFF_NT);
  int* tRoute = (int*)(ws + OFF_TROUTE);
  int* tRow   = (int*)(ws + OFF_TROW);
  int* tok    = (int*)(ws + OFF_TOK);
  unsigned short* Xg  = (unsigned short*)(ws + OFF_XG);
  unsigned short* H   = (unsigned short*)(ws + OFF_H);
  unsigned short* W1T = (unsigned short*)(ws + OFF_W1T);
  unsigned short* W2T = (unsigned short*)(ws + OFF_W2T);

  hipMemsetAsync(ws, 0, 4096, stream);                              // counters/meta
  hipMemsetAsync(ws + OFF_TOK, 0xFF, (size_t)PADROWS * 4, stream);  // tok = -1
  hipMemsetAsync(ws + OFF_XG, 0, (size_t)PADROWS * D_ * 2, stream); // zero padding rows

  cr_count<<<T_TOK / 256, 256, 0, stream>>>(route, counts);
  cr_plan<<<1, 64, 0, stream>>>(counts, padOff, nT, tRoute, tRow);
  cr_scatter<<<T_TOK, 192, 0, stream>>>(X, route, padOff, curs, tok, Xg);

  cr_transpose<D_, F_><<<dim3(D_ / 64, F_ / 64, R_), 256, 0, stream>>>(W1, W1T);
  cr_transpose<F_, V_><<<dim3(F_ / 64, V_ / 64, R_), 256, 0, stream>>>(W2, W2T);

  cr_gemm<D_, F_, 0><<<MAXTILES * (F_ / BN), 256, 0, stream>>>(
      Xg, W1T, b1, nT, tRoute, tRow, tok, H, nullptr);
  cr_gemm<F_, V_, 1><<<MAXTILES * (V_ / BN), 256, 0, stream>>>(
      H, W2T, b2, nT, tRoute, tRow, tok, nullptr, out);

  cr_softmax<<<T_TOK, 256, 0, stream>>>(out);
}

// Round 6
// 639.904 us; speedup vs baseline: 1.0190x; 1.0102x over previous
//
#include <hip/hip_runtime.h>

// CategoryRouter: per-token routed 2-layer MLP head + softmax.
// B=4,S=1024 (T=4096 tokens), D=768, F=3072, V=2048, R=8.
// Round 6: (1) T2 LDS swizzle (pre-swizzled global src + XOR read) — round-5
// showed 3.05e7 bank conflicts = ~11.5 cyc/ds_read_b128; (2) 128^2 m97-exact
// single-buffer tile (2x AI, dbuf was measured-null); (3) GEMM2 split-K=2
// with fp32 atomicAdd into zeroed d_out, bias folded into softmax.

typedef __attribute__((ext_vector_type(8))) short    s16x8;
typedef __attribute__((ext_vector_type(4))) float    f32x4;

#define T_TOK 4096
#define D_    768
#define F_    3072
#define V_    2048
#define R_    8
#define BM    128
#define BN    128
#define BK    64
#define MAXTILES 40      // sum ceil(c_r/128) <= 32+8
#define PADROWS  5120    // 40*128

// ---- workspace layout (bytes) ----
#define OFF_COUNTS  ((size_t)0)     // 8 int
#define OFF_CURS    ((size_t)64)    // 8 int
#define OFF_PADOFF  ((size_t)128)   // 9 int
#define OFF_NT      ((size_t)192)   // 1 int
#define OFF_TROUTE  ((size_t)256)   // MAXTILES int
#define OFF_TROW    ((size_t)1024)  // MAXTILES int
#define OFF_TOK     ((size_t)4096)                                  // PADROWS int
#define OFF_XG      ((size_t)32768)                                 // PADROWS*D bf16
#define OFF_H       (OFF_XG  + (size_t)PADROWS*D_*2)                // PADROWS*F bf16
#define OFF_W1T     (OFF_H   + (size_t)PADROWS*F_*2)                // R*F*D bf16 ([R][F][D])
#define OFF_W2T     (OFF_W1T + (size_t)R_*F_*D_*2)                  // R*V*F bf16 ([R][V][K])

static __device__ __forceinline__ unsigned short f2bf(float f) {
  union { float f; unsigned int u; } x; x.f = f;
  unsigned int r = x.u + 0x7FFFu + ((x.u >> 16) & 1u);   // RNE
  return (unsigned short)(r >> 16);
}

// global -> LDS direct copy, 16B per lane. LDS dest must be wave-uniform
// base; HW writes base + lane*16 (m104/m108). Global src is per-lane.
static __device__ __forceinline__ void gload_lds16(const unsigned short* g,
                                                   unsigned short* l) {
  __builtin_amdgcn_global_load_lds(
      (const __attribute__((address_space(1))) unsigned int*)(const void*)g,
      (__attribute__((address_space(3))) unsigned int*)(void*)l, 16, 0, 0);
}

// ---------------- routing ----------------
__global__ void cr_count(const int* __restrict__ route, int* __restrict__ counts) {
  int t = blockIdx.x * blockDim.x + threadIdx.x;
  if (t < T_TOK) atomicAdd(&counts[route[t]], 1);
}

__global__ void cr_plan(const int* __restrict__ counts, int* __restrict__ padOff,
                        int* __restrict__ nTiles, int* __restrict__ tRoute,
                        int* __restrict__ tRow) {
  if (threadIdx.x != 0 || blockIdx.x != 0) return;
  int off = 0, tiles = 0;
  for (int r = 0; r < R_; ++r) {
    padOff[r] = off;
    int nt = (counts[r] + BM - 1) / BM;
    for (int i = 0; i < nt; ++i) { tRoute[tiles] = r; tRow[tiles] = off + i * BM; ++tiles; }
    off += nt * BM;
  }
  padOff[R_] = off;
  *nTiles = tiles;
}

// one block (192 thr) per token: claim slot, gather+convert its x row to bf16
__global__ void cr_scatter(const float* __restrict__ X, const int* __restrict__ route,
                           const int* __restrict__ padOff, int* __restrict__ curs,
                           int* __restrict__ tok, unsigned short* __restrict__ Xg) {
  __shared__ int spos;
  int t = blockIdx.x;
  if (threadIdx.x == 0) {
    int r = route[t];
    int p = padOff[r] + atomicAdd(&curs[r], 1);
    tok[p] = t;
    spos = p;
  }
  __syncthreads();
  int pos = spos;
  float4 v = reinterpret_cast<const float4*>(X + (size_t)t * D_)[threadIdx.x];
  ushort4 o;
  o.x = f2bf(v.x); o.y = f2bf(v.y); o.z = f2bf(v.z); o.w = f2bf(v.w);
  *reinterpret_cast<ushort4*>(Xg + (size_t)pos * D_ + threadIdx.x * 4) = o;
}

// ---------------- weight transpose + fp32->bf16 ----------------
// in: W [R][K][N] fp32 ; out: Wt [R][N][K] bf16.  128(k) x 64(n) tiles,
// 256 thr; writes are 256B-contiguous runs per n-row.
template <int K, int N>
__global__ void cr_transpose(const float* __restrict__ W, unsigned short* __restrict__ Wt) {
  __shared__ float tile[128][65];
  int r = blockIdx.z;
  const float* Wr = W + (size_t)r * K * N;
  unsigned short* Wtr = Wt + (size_t)r * N * K;
  int k0 = blockIdx.x * 128, n0 = blockIdx.y * 64;
  int t = threadIdx.x;
  int cb = (t & 15) * 4, rb = t >> 4;     // 16 thr cover a 64-f32 row
#pragma unroll
  for (int i = 0; i < 8; ++i) {
    int k = rb + i * 16;
    float4 v = *reinterpret_cast<const float4*>(Wr + (size_t)(k0 + k) * N + n0 + cb);
    tile[k][cb] = v.x; tile[k][cb + 1] = v.y; tile[k][cb + 2] = v.z; tile[k][cb + 3] = v.w;
  }
  __syncthreads();
  int nl = t >> 3, kc = (t & 7) * 16;     // 8 thr cover 128 k of one n-row
#pragma unroll
  for (int np = 0; np < 2; ++np) {
    int n = nl + np * 32;
    alignas(16) unsigned short o[16];
#pragma unroll
    for (int j = 0; j < 16; ++j) o[j] = f2bf(tile[kc + j][n]);
    unsigned short* dst = Wtr + (size_t)(n0 + n) * K + k0 + kc;
    *reinterpret_cast<s16x8*>(dst)     = *reinterpret_cast<const s16x8*>(&o[0]);
    *reinterpret_cast<s16x8*>(dst + 8) = *reinterpret_cast<const s16x8*>(&o[8]);
  }
}

// ---------------- grouped GEMM ----------------
// A [PADROWS][K] bf16 row-major; Wt [R][N][K] bf16 (K-contiguous per col).
// 128x128 tile, BK=64, single-buffer 2-barrier (m97-exact), 4 waves 2x2,
// acc[4][4]. LDS swizzled (T2): staging lane l loads k-run ((l&7)^(l>>3)),
// fragment reads XOR (row&7)<<3 into the k-element index -> conflict-free.
// MODE 0: H = relu(A@W + b) bf16.  MODE 1 (KSLICES=2): atomicAdd fp32 into
// Fout[tok[row]] (d_out pre-zeroed; bias added later in softmax).
template <int K, int N, int MODE, int KSLICES>
__global__ __launch_bounds__(256) void cr_gemm(
    const unsigned short* __restrict__ A, const unsigned short* __restrict__ Wt,
    const float* __restrict__ bias, const int* __restrict__ nTiles,
    const int* __restrict__ tRoute, const int* __restrict__ tRow,
    const int* __restrict__ tok, unsigned short* __restrict__ Hout,
    float* __restrict__ Fout) {
  constexpr int NY = N / BN;
  constexpr int KS_LEN = K / KSLICES;          // k extent per slice
  int bid = blockIdx.x;
  int ks  = bid / (MAXTILES * NY);
  int rem = bid - ks * (MAXTILES * NY);
  int y   = rem / MAXTILES;                    // mt fastest: B-panel reuse
  int mt  = rem - y * MAXTILES;
  if (mt >= *nTiles) return;
  int route = tRoute[mt], row0 = tRow[mt];
  int col0 = y * BN;
  int kbase = ks * KS_LEN;
  const unsigned short* Ag = A + (size_t)row0 * K + kbase;
  const unsigned short* Bg = Wt + ((size_t)route * N + col0) * K + kbase;

  __shared__ __align__(16) unsigned short As[BM * BK];  // 16 KB (swizzled)
  __shared__ __align__(16) unsigned short Bs[BN * BK];  // 16 KB (swizzled)

  int tid = threadIdx.x, lane = tid & 63, w = tid >> 6;
  int wr = w >> 1, wc = w & 1;   // 2x2 wave grid, 64x64 out each
  int rl = lane >> 3;            // staging: row within 8-row chunk
  int kx = ((lane & 7) ^ rl) * 8;  // staging: pre-swizzled k-run (T2 inverse)
  int frow = lane & 15;          // fragment row/col
  int fk   = (lane >> 4) * 8;    // fragment k base
  int rx   = (frow & 7) << 3;    // read-side swizzle XOR (elems)

  f32x4 acc[4][4] = {};

  for (int kt = 0; kt < KS_LEN; kt += BK) {
    // 32 chunks of 8 rows x 64 k (1 KB): 0..15 -> As, 16..31 -> Bs.
    // chunk = j*4+w wave-uniform; HW writes LDS base + lane*16B (linear).
#pragma unroll
    for (int j = 0; j < 4; ++j) {
      int c = j * 4 + w;
      gload_lds16(Ag + (size_t)(c * 8 + rl) * K + kt + kx, As + c * 512);
    }
#pragma unroll
    for (int j = 0; j < 4; ++j) {
      int c = j * 4 + w;
      gload_lds16(Bg + (size_t)(c * 8 + rl) * K + kt + kx, Bs + c * 512);
    }
    __syncthreads();
#pragma unroll
    for (int kk = 0; kk < 2; ++kk) {
      s16x8 a[4], b[4];
#pragma unroll
      for (int mi = 0; mi < 4; ++mi)
        a[mi] = *reinterpret_cast<const s16x8*>(
            &As[(wr * 64 + mi * 16 + frow) * BK + ((kk * 32 + fk) ^ rx)]);
#pragma unroll
      for (int ni = 0; ni < 4; ++ni)
        b[ni] = *reinterpret_cast<const s16x8*>(
            &Bs[(wc * 64 + ni * 16 + frow) * BK + ((kk * 32 + fk) ^ rx)]);
#pragma unroll
      for (int mi = 0; mi < 4; ++mi)
#pragma unroll
        for (int ni = 0; ni < 4; ++ni)
          acc[mi][ni] = __builtin_amdgcn_mfma_f32_16x16x32_bf16(
              a[mi], b[ni], acc[mi][ni], 0, 0, 0);
    }
    __syncthreads();
  }

  // epilogue: C/D layout col=lane&15, row=(lane>>4)*4+j  (m89/m91-verified)
  int crow = (lane >> 4) * 4;
  int ccol = lane & 15;
#pragma unroll
  for (int mi = 0; mi < 4; ++mi) {
#pragma unroll
    for (int ni = 0; ni < 4; ++ni) {
      int gcol = col0 + wc * 64 + ni * 16 + ccol;
#pragma unroll
      for (int j = 0; j < 4; ++j) {
        int prow = row0 + wr * 64 + mi * 16 + crow + j;
        float v = acc[mi][ni][j];
        if (MODE == 0) {
          v = fmaxf(v + bias[(size_t)route * N + gcol], 0.f);
          Hout[(size_t)prow * N + gcol] = f2bf(v);
        } else {
          int tk = tok[prow];
          if (tk >= 0) atomicAdd(&Fout[(size_t)tk * N + gcol], v);
        }
      }
    }
  }
}

// ------- softmax with fused bias (in place, one block per token) -------
__global__ void cr_softmax(float* __restrict__ out, const int* __restrict__ route,
                           const float* __restrict__ b2) {
  int row = blockIdx.x;
  int r = route[row];
  float* p = out + (size_t)row * V_;
  const float* bp = b2 + (size_t)r * V_;
  int t = threadIdx.x;
  float4 v0 = reinterpret_cast<float4*>(p)[t];
  float4 v1 = reinterpret_cast<float4*>(p)[t + 256];
  float4 b0 = reinterpret_cast<const float4*>(bp)[t];
  float4 b1 = reinterpret_cast<const float4*>(bp)[t + 256];
  v0.x += b0.x; v0.y += b0.y; v0.z += b0.z; v0.w += b0.w;
  v1.x += b1.x; v1.y += b1.y; v1.z += b1.z; v1.w += b1.w;
  float m = fmaxf(fmaxf(fmaxf(v0.x, v0.y), fmaxf(v0.z, v0.w)),
                  fmaxf(fmaxf(v1.x, v1.y), fmaxf(v1.z, v1.w)));
#pragma unroll
  for (int o = 32; o; o >>= 1) m = fmaxf(m, __shfl_xor(m, o));
  __shared__ float sm[4], ss[4];
  int w = t >> 6;
  if ((t & 63) == 0) sm[w] = m;
  __syncthreads();
  m = fmaxf(fmaxf(sm[0], sm[1]), fmaxf(sm[2], sm[3]));
  v0.x = expf(v0.x - m); v0.y = expf(v0.y - m); v0.z = expf(v0.z - m); v0.w = expf(v0.w - m);
  v1.x = expf(v1.x - m); v1.y = expf(v1.y - m); v1.z = expf(v1.z - m); v1.w = expf(v1.w - m);
  float s = v0.x + v0.y + v0.z + v0.w + v1.x + v1.y + v1.z + v1.w;
#pragma unroll
  for (int o = 32; o; o >>= 1) s += __shfl_xor(s, o);
  if ((t & 63) == 0) ss[w] = s;
  __syncthreads();
  s = ss[0] + ss[1] + ss[2] + ss[3];
  float inv = 1.f / s;
  v0.x *= inv; v0.y *= inv; v0.z *= inv; v0.w *= inv;
  v1.x *= inv; v1.y *= inv; v1.z *= inv; v1.w *= inv;
  reinterpret_cast<float4*>(p)[t] = v0;
  reinterpret_cast<float4*>(p)[t + 256] = v1;
}

extern "C" void kernel_launch(void* const* d_in, const int* in_sizes, int n_in,
                              void* d_out, int out_size, void* d_ws, size_t ws_size,
                              hipStream_t stream) {
  const float* X      = (const float*)d_in[0];
  const int*   route  = (const int*)d_in[1];
  const float* W1     = (const float*)d_in[2];
  const float* b1     = (const float*)d_in[3];
  const float* W2     = (const float*)d_in[4];
  const float* b2     = (const float*)d_in[5];
  float*       out    = (float*)d_out;
  char*        ws     = (char*)d_ws;

  int* counts = (int*)(ws + OFF_COUNTS);
  int* curs   = (int*)(ws + OFF_CURS);
  int* padOff = (int*)(ws + OFF_PADOFF);
  int* nT     = (int*)(ws + OFF_NT);
  int* tRoute = (int*)(ws + OFF_TROUTE);
  int* tRow   = (int*)(ws + OFF_TROW);
  int* tok    = (int*)(ws + OFF_TOK);
  unsigned short* Xg  = (unsigned short*)(ws + OFF_XG);
  unsigned short* H   = (unsigned short*)(ws + OFF_H);
  unsigned short* W1T = (unsigned short*)(ws + OFF_W1T);
  unsigned short* W2T = (unsigned short*)(ws + OFF_W2T);

  hipMemsetAsync(ws, 0, 4096, stream);                              // counters/meta
  hipMemsetAsync(ws + OFF_TOK, 0xFF, (size_t)PADROWS * 4, stream);  // tok = -1
  hipMemsetAsync(ws + OFF_XG, 0, (size_t)PADROWS * D_ * 2, stream); // zero pad rows
  hipMemsetAsync(out, 0, (size_t)T_TOK * V_ * 4, stream);           // atomic target

  cr_count<<<T_TOK / 256, 256, 0, stream>>>(route, counts);
  cr_plan<<<1, 64, 0, stream>>>(counts, padOff, nT, tRoute, tRow);
  cr_scatter<<<T_TOK, 192, 0, stream>>>(X, route, padOff, curs, tok, Xg);

  cr_transpose<D_, F_><<<dim3(D_ / 128, F_ / 64, R_), 256, 0, stream>>>(W1, W1T);
  cr_transpose<F_, V_><<<dim3(F_ / 128, V_ / 64, R_), 256, 0, stream>>>(W2, W2T);

  cr_gemm<D_, F_, 0, 1><<<MAXTILES * (F_ / BN), 256, 0, stream>>>(
      Xg, W1T, b1, nT, tRoute, tRow, tok, H, nullptr);
  cr_gemm<F_, V_, 1, 2><<<MAXTILES * (V_ / BN) * 2, 256, 0, stream>>>(
      H, W2T, nullptr, nT, tRoute, tRow, tok, nullptr, out);

  cr_softmax<<<T_TOK, 256, 0, stream>>>(out, route, b2);
}

// Round 7
// 622.274 us; speedup vs baseline: 1.0478x; 1.0283x over previous
//
#include <hip/hip_runtime.h>

// CategoryRouter: per-token routed 2-layer MLP head + softmax.
// B=4,S=1024 (T=4096 tokens), D=768, F=3072, V=2048, R=8.
// Round 7: T4 counted-vmcnt pipeline. Rounds 2-6 all pinned at ~156us/GEMM
// regardless of tile/swizzle/splitK -> the invariant was the vmcnt(0) drain
// per K-step (m233: 72% of 2-phase time). Now: dbuf LDS, stage(next) then
// s_waitcnt vmcnt(8) + raw s_barrier (loads stay in flight across barriers,
// m218 pattern). Dropped: splitK atomics, memset(out); bias back in GEMM2.

typedef __attribute__((ext_vector_type(8))) short    s16x8;
typedef __attribute__((ext_vector_type(4))) float    f32x4;

#define T_TOK 4096
#define D_    768
#define F_    3072
#define V_    2048
#define R_    8
#define BM    128
#define BN    128
#define BK    64
#define MAXTILES 40      // sum ceil(c_r/128) <= 32+8
#define PADROWS  5120    // 40*128

// ---- workspace layout (bytes) ----
#define OFF_COUNTS  ((size_t)0)     // 8 int
#define OFF_CURS    ((size_t)64)    // 8 int
#define OFF_PADOFF  ((size_t)128)   // 9 int
#define OFF_NT      ((size_t)192)   // 1 int
#define OFF_TROUTE  ((size_t)256)   // MAXTILES int
#define OFF_TROW    ((size_t)1024)  // MAXTILES int
#define OFF_TOK     ((size_t)4096)                                  // PADROWS int
#define OFF_XG      ((size_t)32768)                                 // PADROWS*D bf16
#define OFF_H       (OFF_XG  + (size_t)PADROWS*D_*2)                // PADROWS*F bf16
#define OFF_W1T     (OFF_H   + (size_t)PADROWS*F_*2)                // R*F*D bf16 ([R][F][D])
#define OFF_W2T     (OFF_W1T + (size_t)R_*F_*D_*2)                  // R*V*F bf16 ([R][V][K])

static __device__ __forceinline__ unsigned short f2bf(float f) {
  union { float f; unsigned int u; } x; x.f = f;
  unsigned int r = x.u + 0x7FFFu + ((x.u >> 16) & 1u);   // RNE
  return (unsigned short)(r >> 16);
}

// global -> LDS direct copy, 16B per lane. LDS dest must be wave-uniform
// base; HW writes base + lane*16 (m104/m108). Global src is per-lane.
static __device__ __forceinline__ void gload_lds16(const unsigned short* g,
                                                   unsigned short* l) {
  __builtin_amdgcn_global_load_lds(
      (const __attribute__((address_space(1))) unsigned int*)(const void*)g,
      (__attribute__((address_space(3))) unsigned int*)(void*)l, 16, 0, 0);
}

// ---------------- routing ----------------
__global__ void cr_count(const int* __restrict__ route, int* __restrict__ counts) {
  int t = blockIdx.x * blockDim.x + threadIdx.x;
  if (t < T_TOK) atomicAdd(&counts[route[t]], 1);
}

__global__ void cr_plan(const int* __restrict__ counts, int* __restrict__ padOff,
                        int* __restrict__ nTiles, int* __restrict__ tRoute,
                        int* __restrict__ tRow) {
  if (threadIdx.x != 0 || blockIdx.x != 0) return;
  int off = 0, tiles = 0;
  for (int r = 0; r < R_; ++r) {
    padOff[r] = off;
    int nt = (counts[r] + BM - 1) / BM;
    for (int i = 0; i < nt; ++i) { tRoute[tiles] = r; tRow[tiles] = off + i * BM; ++tiles; }
    off += nt * BM;
  }
  padOff[R_] = off;
  *nTiles = tiles;
}

// one block (192 thr) per token: claim slot, gather+convert its x row to bf16
__global__ void cr_scatter(const float* __restrict__ X, const int* __restrict__ route,
                           const int* __restrict__ padOff, int* __restrict__ curs,
                           int* __restrict__ tok, unsigned short* __restrict__ Xg) {
  __shared__ int spos;
  int t = blockIdx.x;
  if (threadIdx.x == 0) {
    int r = route[t];
    int p = padOff[r] + atomicAdd(&curs[r], 1);
    tok[p] = t;
    spos = p;
  }
  __syncthreads();
  int pos = spos;
  float4 v = reinterpret_cast<const float4*>(X + (size_t)t * D_)[threadIdx.x];
  ushort4 o;
  o.x = f2bf(v.x); o.y = f2bf(v.y); o.z = f2bf(v.z); o.w = f2bf(v.w);
  *reinterpret_cast<ushort4*>(Xg + (size_t)pos * D_ + threadIdx.x * 4) = o;
}

// ---------------- weight transpose + fp32->bf16 ----------------
// in: W [R][K][N] fp32 ; out: Wt [R][N][K] bf16.  128(k) x 64(n) tiles,
// 256 thr; writes are 256B-contiguous runs per n-row.
template <int K, int N>
__global__ void cr_transpose(const float* __restrict__ W, unsigned short* __restrict__ Wt) {
  __shared__ float tile[128][65];
  int r = blockIdx.z;
  const float* Wr = W + (size_t)r * K * N;
  unsigned short* Wtr = Wt + (size_t)r * N * K;
  int k0 = blockIdx.x * 128, n0 = blockIdx.y * 64;
  int t = threadIdx.x;
  int cb = (t & 15) * 4, rb = t >> 4;     // 16 thr cover a 64-f32 row
#pragma unroll
  for (int i = 0; i < 8; ++i) {
    int k = rb + i * 16;
    float4 v = *reinterpret_cast<const float4*>(Wr + (size_t)(k0 + k) * N + n0 + cb);
    tile[k][cb] = v.x; tile[k][cb + 1] = v.y; tile[k][cb + 2] = v.z; tile[k][cb + 3] = v.w;
  }
  __syncthreads();
  int nl = t >> 3, kc = (t & 7) * 16;     // 8 thr cover 128 k of one n-row
#pragma unroll
  for (int np = 0; np < 2; ++np) {
    int n = nl + np * 32;
    alignas(16) unsigned short o[16];
#pragma unroll
    for (int j = 0; j < 16; ++j) o[j] = f2bf(tile[kc + j][n]);
    unsigned short* dst = Wtr + (size_t)(n0 + n) * K + k0 + kc;
    *reinterpret_cast<s16x8*>(dst)     = *reinterpret_cast<const s16x8*>(&o[0]);
    *reinterpret_cast<s16x8*>(dst + 8) = *reinterpret_cast<const s16x8*>(&o[8]);
  }
}

// ---------------- grouped GEMM (T4 counted-vmcnt pipeline) ----------------
// A [PADROWS][K] bf16 row-major; Wt [R][N][K] bf16 (K-contiguous per col).
// 128x128 tile, BK=64, dbuf LDS, 4 waves 2x2, acc[4][4], T2 swizzle
// (pre-swizzled global src + XOR read; round-6 verified 0 conflicts).
// Per K-step: stage(next) -> vmcnt(8) -> s_barrier -> MFMA -> sched_barrier
// -> s_barrier. Loads never drain to 0 in the main loop (m218).
// MODE 0: H = relu(A@W + b) bf16.  MODE 1: out[tok[row]] = A@W + b fp32.
template <int K, int N, int MODE>
__global__ __launch_bounds__(256) void cr_gemm(
    const unsigned short* __restrict__ A, const unsigned short* __restrict__ Wt,
    const float* __restrict__ bias, const int* __restrict__ nTiles,
    const int* __restrict__ tRoute, const int* __restrict__ tRow,
    const int* __restrict__ tok, unsigned short* __restrict__ Hout,
    float* __restrict__ Fout) {
  constexpr int NSTEP = K / BK;
  int bid = blockIdx.x;
  int y   = bid / MAXTILES;        // mt fastest: B-panel L2 reuse
  int mt  = bid - y * MAXTILES;
  if (mt >= *nTiles) return;       // block-uniform: safe with barriers below
  int route = tRoute[mt], row0 = tRow[mt];
  int col0 = y * BN;
  const unsigned short* Ag = A + (size_t)row0 * K;
  const unsigned short* Bg = Wt + ((size_t)route * N + col0) * K;

  __shared__ __align__(16) unsigned short As[2][BM * BK];  // 2x16 KB (swizzled)
  __shared__ __align__(16) unsigned short Bs[2][BN * BK];  // 2x16 KB (swizzled)

  int tid = threadIdx.x, lane = tid & 63, w = tid >> 6;
  int wr = w >> 1, wc = w & 1;     // 2x2 wave grid, 64x64 out each
  int rl = lane >> 3;              // staging: row within 8-row chunk
  int kx = ((lane & 7) ^ rl) * 8;  // staging: pre-swizzled k-run (T2 inverse)
  int frow = lane & 15;            // fragment row/col
  int fk   = (lane >> 4) * 8;      // fragment k base
  int rx   = (frow & 7) << 3;      // read-side swizzle XOR (elems)

  f32x4 acc[4][4] = {};

  // 8 loads per wave per K-step: chunks c=j*4+w; 16 chunks As + 16 Bs per
  // block (1 KB each); lane LDS offset = 16*lane B (linear, m104-safe).
  auto stage = [&](int buf, int kt) {
#pragma unroll
    for (int j = 0; j < 4; ++j) {
      int c = j * 4 + w;
      gload_lds16(Ag + (size_t)(c * 8 + rl) * K + kt + kx, &As[buf][c * 512]);
    }
#pragma unroll
    for (int j = 0; j < 4; ++j) {
      int c = j * 4 + w;
      gload_lds16(Bg + (size_t)(c * 8 + rl) * K + kt + kx, &Bs[buf][c * 512]);
    }
  };
  auto compute = [&](int buf) {
#pragma unroll
    for (int kk = 0; kk < 2; ++kk) {
      s16x8 a[4], b[4];
#pragma unroll
      for (int mi = 0; mi < 4; ++mi)
        a[mi] = *reinterpret_cast<const s16x8*>(
            &As[buf][(wr * 64 + mi * 16 + frow) * BK + ((kk * 32 + fk) ^ rx)]);
#pragma unroll
      for (int ni = 0; ni < 4; ++ni)
        b[ni] = *reinterpret_cast<const s16x8*>(
            &Bs[buf][(wc * 64 + ni * 16 + frow) * BK + ((kk * 32 + fk) ^ rx)]);
#pragma unroll
      for (int mi = 0; mi < 4; ++mi)
#pragma unroll
        for (int ni = 0; ni < 4; ++ni)
          acc[mi][ni] = __builtin_amdgcn_mfma_f32_16x16x32_bf16(
              a[mi], b[ni], acc[mi][ni], 0, 0, 0);
    }
  };

  stage(0, 0);                                     // prologue: buf0 in flight
  for (int t = 0; t < NSTEP; ++t) {
    int buf = t & 1;
    if (t + 1 < NSTEP) {
      stage(buf ^ 1, (t + 1) * BK);                // next tile: 8 more loads
      // my oldest 8 (current tile) landed when <=8 remain outstanding;
      // every wave does this before the barrier -> whole tile valid.
      asm volatile("s_waitcnt vmcnt(8)" ::: "memory");
    } else {
      asm volatile("s_waitcnt vmcnt(0)" ::: "memory");
    }
    __builtin_amdgcn_s_barrier();                  // tile[buf] ready
    __builtin_amdgcn_sched_barrier(0);             // no hoist above barrier
    compute(buf);
    __builtin_amdgcn_sched_barrier(0);             // no sink below barrier
    __builtin_amdgcn_s_barrier();                  // all reads of buf done
  }

  // epilogue: C/D layout col=lane&15, row=(lane>>4)*4+j  (m89/m91-verified)
  int crow = (lane >> 4) * 4;
  int ccol = lane & 15;
#pragma unroll
  for (int mi = 0; mi < 4; ++mi) {
#pragma unroll
    for (int ni = 0; ni < 4; ++ni) {
      int gcol = col0 + wc * 64 + ni * 16 + ccol;
      float bv = bias[(size_t)route * N + gcol];
#pragma unroll
      for (int j = 0; j < 4; ++j) {
        int prow = row0 + wr * 64 + mi * 16 + crow + j;
        float v = acc[mi][ni][j] + bv;
        if (MODE == 0) {
          Hout[(size_t)prow * N + gcol] = f2bf(fmaxf(v, 0.f));
        } else {
          int tk = tok[prow];
          if (tk >= 0) Fout[(size_t)tk * N + gcol] = v;
        }
      }
    }
  }
}

// ---------------- softmax (in place over V=2048, one block per token) ----------
__global__ void cr_softmax(float* __restrict__ out) {
  int row = blockIdx.x;
  float* p = out + (size_t)row * V_;
  int t = threadIdx.x;
  float4 v0 = reinterpret_cast<float4*>(p)[t];
  float4 v1 = reinterpret_cast<float4*>(p)[t + 256];
  float m = fmaxf(fmaxf(fmaxf(v0.x, v0.y), fmaxf(v0.z, v0.w)),
                  fmaxf(fmaxf(v1.x, v1.y), fmaxf(v1.z, v1.w)));
#pragma unroll
  for (int o = 32; o; o >>= 1) m = fmaxf(m, __shfl_xor(m, o));
  __shared__ float sm[4], ss[4];
  int w = t >> 6;
  if ((t & 63) == 0) sm[w] = m;
  __syncthreads();
  m = fmaxf(fmaxf(sm[0], sm[1]), fmaxf(sm[2], sm[3]));
  v0.x = expf(v0.x - m); v0.y = expf(v0.y - m); v0.z = expf(v0.z - m); v0.w = expf(v0.w - m);
  v1.x = expf(v1.x - m); v1.y = expf(v1.y - m); v1.z = expf(v1.z - m); v1.w = expf(v1.w - m);
  float s = v0.x + v0.y + v0.z + v0.w + v1.x + v1.y + v1.z + v1.w;
#pragma unroll
  for (int o = 32; o; o >>= 1) s += __shfl_xor(s, o);
  if ((t & 63) == 0) ss[w] = s;
  __syncthreads();
  s = ss[0] + ss[1] + ss[2] + ss[3];
  float inv = 1.f / s;
  v0.x *= inv; v0.y *= inv; v0.z *= inv; v0.w *= inv;
  v1.x *= inv; v1.y *= inv; v1.z *= inv; v1.w *= inv;
  reinterpret_cast<float4*>(p)[t] = v0;
  reinterpret_cast<float4*>(p)[t + 256] = v1;
}

extern "C" void kernel_launch(void* const* d_in, const int* in_sizes, int n_in,
                              void* d_out, int out_size, void* d_ws, size_t ws_size,
                              hipStream_t stream) {
  const float* X      = (const float*)d_in[0];
  const int*   route  = (const int*)d_in[1];
  const float* W1     = (const float*)d_in[2];
  const float* b1     = (const float*)d_in[3];
  const float* W2     = (const float*)d_in[4];
  const float* b2     = (const float*)d_in[5];
  float*       out    = (float*)d_out;
  char*        ws     = (char*)d_ws;

  int* counts = (int*)(ws + OFF_COUNTS);
  int* curs   = (int*)(ws + OFF_CURS);
  int* padOff = (int*)(ws + OFF_PADOFF);
  int* nT     = (int*)(ws + OFF_NT);
  int* tRoute = (int*)(ws + OFF_TROUTE);
  int* tRow   = (int*)(ws + OFF_TROW);
  int* tok    = (int*)(ws + OFF_TOK);
  unsigned short* Xg  = (unsigned short*)(ws + OFF_XG);
  unsigned short* H   = (unsigned short*)(ws + OFF_H);
  unsigned short* W1T = (unsigned short*)(ws + OFF_W1T);
  unsigned short* W2T = (unsigned short*)(ws + OFF_W2T);

  hipMemsetAsync(ws, 0, 4096, stream);                              // counters/meta
  hipMemsetAsync(ws + OFF_TOK, 0xFF, (size_t)PADROWS * 4, stream);  // tok = -1
  hipMemsetAsync(ws + OFF_XG, 0, (size_t)PADROWS * D_ * 2, stream); // zero pad rows

  cr_count<<<T_TOK / 256, 256, 0, stream>>>(route, counts);
  cr_plan<<<1, 64, 0, stream>>>(counts, padOff, nT, tRoute, tRow);
  cr_scatter<<<T_TOK, 192, 0, stream>>>(X, route, padOff, curs, tok, Xg);

  cr_transpose<D_, F_><<<dim3(D_ / 128, F_ / 64, R_), 256, 0, stream>>>(W1, W1T);
  cr_transpose<F_, V_><<<dim3(F_ / 128, V_ / 64, R_), 256, 0, stream>>>(W2, W2T);

  cr_gemm<D_, F_, 0><<<MAXTILES * (F_ / BN), 256, 0, stream>>>(
      Xg, W1T, b1, nT, tRoute, tRow, tok, H, nullptr);
  cr_gemm<F_, V_, 1><<<MAXTILES * (V_ / BN), 256, 0, stream>>>(
      H, W2T, b2, nT, tRoute, tRow, tok, nullptr, out);

  cr_softmax<<<T_TOK, 256, 0, stream>>>(out);
}